// Round 1
// baseline (354.782 us; speedup 1.0000x reference)
//
#include <hip/hip_runtime.h>

typedef unsigned short u16;
typedef __bf16 bf16;
typedef __bf16 bf16x8 __attribute__((ext_vector_type(8)));
typedef float f32x4 __attribute__((ext_vector_type(4)));
typedef unsigned short u16x8 __attribute__((ext_vector_type(8)));
typedef unsigned short u16x4 __attribute__((ext_vector_type(4)));

#define DEVI static __device__ __forceinline__

DEVI u16 f2bf(float f) {
  unsigned u = __builtin_bit_cast(unsigned, f);
  return (u16)((u + 0x7fffu + ((u >> 16) & 1u)) >> 16);
}
DEVI float bf2f(u16 h) { return __builtin_bit_cast(float, (unsigned)h << 16); }

// ---------------------------------------------------------------- cast fp32->bf16
// ranges (float4 units): x 1048576 | wqkv 49152 | wout 16384 | w1 65536 | wv 65536 | w2 65536
__global__ __launch_bounds__(256) void k_cast(const float* __restrict__ x,
                                              const float* __restrict__ wqkv,
                                              const float* __restrict__ wout,
                                              const float* __restrict__ w1,
                                              const float* __restrict__ wv,
                                              const float* __restrict__ w2,
                                              u16* __restrict__ dst0) {
  long i = (long)blockIdx.x * 256 + threadIdx.x;
  const float* src;
  u16* dst;
  long off;
  if (i < 1048576)       { src = x;    dst = dst0;           off = i; }
  else if (i < 1097728)  { src = wqkv; dst = dst0 + 4194304; off = i - 1048576; }
  else if (i < 1114112)  { src = wout; dst = dst0 + 4390912; off = i - 1097728; }
  else if (i < 1179648)  { src = w1;   dst = dst0 + 4456448; off = i - 1114112; }
  else if (i < 1245184)  { src = wv;   dst = dst0 + 4718592; off = i - 1179648; }
  else                   { src = w2;   dst = dst0 + 4980736; off = i - 1245184; }
  float4 f = reinterpret_cast<const float4*>(src)[off];
  u16x4 o;
  o[0] = f2bf(f.x); o[1] = f2bf(f.y); o[2] = f2bf(f.z); o[3] = f2bf(f.w);
  reinterpret_cast<u16x4*>(dst)[off] = o;
}

// ---------------------------------------------------------------- GEMM: C = A * B^T (+bias)
// A [M][K] bf16, B rows = out-features [N][K] bf16 (two pointers, split at Nsplit), C [M][N] bf16.
// 128x128 tile, BK=64, 4 waves each 64x64 quadrant, LDS stride 72 (16B-aligned, ~2-way banks).
__global__ __launch_bounds__(256) void k_gemm(const u16* __restrict__ A,
                                              const u16* __restrict__ B0,
                                              const u16* __restrict__ B1,
                                              int Nsplit, const float* __restrict__ bias,
                                              u16* __restrict__ C, int N, int K) {
  __shared__ u16 Alds[128 * 72];
  __shared__ u16 Blds[128 * 72];
  const int m0 = blockIdx.x * 128;
  const int n0 = blockIdx.y * 128;
  const u16* Ap = A + (long)m0 * K;
  const u16* Bp = (n0 < Nsplit) ? (B0 + (long)n0 * K) : (B1 + (long)(n0 - Nsplit) * K);
  const int tid = threadIdx.x;
  const int lane = tid & 63;
  const int wave = tid >> 6;
  const int wr = (wave >> 1) * 64, wc = (wave & 1) * 64;
  const int lr = lane & 15, g = lane >> 4;
  const int srow = tid & 31;
  const int scol = (tid >> 5) << 3;

  f32x4 acc[4][4] = {};
  u16x8 pa[4], pb[4];
  const int nk = K >> 6;
#pragma unroll
  for (int j = 0; j < 4; ++j) {
    pa[j] = *reinterpret_cast<const u16x8*>(Ap + (long)(j * 32 + srow) * K + scol);
    pb[j] = *reinterpret_cast<const u16x8*>(Bp + (long)(j * 32 + srow) * K + scol);
  }
  for (int kt = 0; kt < nk; ++kt) {
    __syncthreads();
#pragma unroll
    for (int j = 0; j < 4; ++j) {
      *reinterpret_cast<u16x8*>(&Alds[(j * 32 + srow) * 72 + scol]) = pa[j];
      *reinterpret_cast<u16x8*>(&Blds[(j * 32 + srow) * 72 + scol]) = pb[j];
    }
    __syncthreads();
    if (kt + 1 < nk) {
      const int k0 = (kt + 1) << 6;
#pragma unroll
      for (int j = 0; j < 4; ++j) {
        pa[j] = *reinterpret_cast<const u16x8*>(Ap + (long)(j * 32 + srow) * K + k0 + scol);
        pb[j] = *reinterpret_cast<const u16x8*>(Bp + (long)(j * 32 + srow) * K + k0 + scol);
      }
    }
#pragma unroll
    for (int kk = 0; kk < 2; ++kk) {
      bf16x8 af[4], bfv[4];
#pragma unroll
      for (int i = 0; i < 4; ++i)
        af[i] = *reinterpret_cast<const bf16x8*>(&Alds[(wr + i * 16 + lr) * 72 + kk * 32 + g * 8]);
#pragma unroll
      for (int i = 0; i < 4; ++i)
        bfv[i] = *reinterpret_cast<const bf16x8*>(&Blds[(wc + i * 16 + lr) * 72 + kk * 32 + g * 8]);
#pragma unroll
      for (int mi = 0; mi < 4; ++mi)
#pragma unroll
        for (int ni = 0; ni < 4; ++ni)
          acc[mi][ni] = __builtin_amdgcn_mfma_f32_16x16x32_bf16(af[mi], bfv[ni], acc[mi][ni], 0, 0, 0);
    }
  }
#pragma unroll
  for (int mi = 0; mi < 4; ++mi) {
#pragma unroll
    for (int ni = 0; ni < 4; ++ni) {
      const int row = m0 + wr + mi * 16 + g * 4;
      const int col = n0 + wc + ni * 16 + lr;
      const float bv = bias ? bias[col] : 0.0f;
#pragma unroll
      for (int r = 0; r < 4; ++r)
        C[(long)(row + r) * N + col] = f2bf(acc[mi][ni][r] + bv);
    }
  }
}

// ---------------------------------------------------------------- flash attention
// qkv [16384][768] bf16 (cols: Q 0..255, K 256..511, V 512..767; head h at h*32).
// Grid 1024: id%64 = bh (XCD locality), id/64 = q-tile of 128 rows. 8 waves x 16 q-rows.
// S^T = mfma(K-frag, Q-frag): lane owns q = lane&15, k-rows (lane>>4)*4+r per 16-frag.
__global__ __launch_bounds__(512) void k_attn(const u16* __restrict__ qkv, u16* __restrict__ o) {
  __shared__ u16 Klds[64 * 40];
  __shared__ u16 Vtlds[32 * 72];
  __shared__ u16 Plds[64 * 132];
  const int id = blockIdx.x;
  const int qt = id >> 6;
  const int bh = id & 63;
  const int b = bh >> 3, h = bh & 7;
  const int tid = threadIdx.x;
  const int wave = tid >> 6, lane = tid & 63;
  const int lq = lane & 15, g = lane >> 4;
  const int q0 = qt * 128;
  const long qrow = (long)(b * 2048 + q0 + wave * 16 + lq);
  u16x8 qraw = *reinterpret_cast<const u16x8*>(qkv + qrow * 768 + h * 32 + g * 8);
  bf16x8 qf;
#pragma unroll
  for (int j = 0; j < 8; ++j) qf[j] = (bf16)(bf2f(qraw[j]) * 0.17677669529663687f);

  float m = -1e30f, l = 0.0f;
  f32x4 oacc[2] = {};
  const f32x4 zero = {0.0f, 0.0f, 0.0f, 0.0f};

  for (int kt = 0; kt < 32; ++kt) {
    __syncthreads();
    const long kbase = (long)(b * 2048 + kt * 64);
    if (tid < 256) {  // waves 0-3 stage K [64][32] -> Klds stride 40
      const int k = tid >> 2, dc = (tid & 3) * 8;
      u16x8 kv = *reinterpret_cast<const u16x8*>(qkv + (kbase + k) * 768 + 256 + h * 32 + dc);
      *reinterpret_cast<u16x8*>(&Klds[k * 40 + dc]) = kv;
    } else {          // waves 4-7 stage V transposed -> Vtlds [32 d][64 k] stride 72
      const int st = tid - 256;
      const int k = st >> 2, dc = (st & 3) * 8;
      u16x8 vv = *reinterpret_cast<const u16x8*>(qkv + (kbase + k) * 768 + 512 + h * 32 + dc);
#pragma unroll
      for (int j = 0; j < 8; ++j) Vtlds[(dc + j) * 72 + k] = vv[j];
    }
    __syncthreads();

    f32x4 s[4];
#pragma unroll
    for (int f = 0; f < 4; ++f) {
      bf16x8 kf = *reinterpret_cast<const bf16x8*>(&Klds[(f * 16 + lq) * 40 + g * 8]);
      s[f] = __builtin_amdgcn_mfma_f32_16x16x32_bf16(kf, qf, zero, 0, 0, 0);
    }

    float tmax = -1e30f;
#pragma unroll
    for (int f = 0; f < 4; ++f)
#pragma unroll
      for (int r = 0; r < 4; ++r) tmax = fmaxf(tmax, s[f][r]);
    tmax = fmaxf(tmax, __shfl_xor(tmax, 16));
    tmax = fmaxf(tmax, __shfl_xor(tmax, 32));
    const float mnew = fmaxf(m, tmax);
    const float alpha = exp2f((m - mnew) * 1.4426950408889634f);
    float rsum = 0.0f;
    float ps[4][4];
#pragma unroll
    for (int f = 0; f < 4; ++f)
#pragma unroll
      for (int r = 0; r < 4; ++r) {
        const float p = exp2f((s[f][r] - mnew) * 1.4426950408889634f);
        ps[f][r] = p;
        rsum += p;
      }
    rsum += __shfl_xor(rsum, 16);
    rsum += __shfl_xor(rsum, 32);
    l = l * alpha + rsum;
    m = mnew;
#pragma unroll
    for (int di = 0; di < 2; ++di)
#pragma unroll
      for (int r = 0; r < 4; ++r) oacc[di][r] *= alpha;

    // P^T strip to per-wave-private LDS columns (no cross-wave sharing -> no barrier)
#pragma unroll
    for (int f = 0; f < 4; ++f)
#pragma unroll
      for (int r = 0; r < 4; ++r)
        Plds[(f * 16 + g * 4 + r) * 132 + wave * 16 + lq] = f2bf(ps[f][r]);

    // O^T += V^T * P^T  (A = Vt contiguous b128, B = P^T from own columns)
#pragma unroll
    for (int ks = 0; ks < 2; ++ks) {
      u16x8 pr;
#pragma unroll
      for (int j = 0; j < 8; ++j) pr[j] = Plds[(ks * 32 + g * 8 + j) * 132 + wave * 16 + lq];
      const bf16x8 pf = __builtin_bit_cast(bf16x8, pr);
#pragma unroll
      for (int di = 0; di < 2; ++di) {
        bf16x8 vf = *reinterpret_cast<const bf16x8*>(&Vtlds[(di * 16 + lq) * 72 + ks * 32 + g * 8]);
        oacc[di] = __builtin_amdgcn_mfma_f32_16x16x32_bf16(vf, pf, oacc[di], 0, 0, 0);
      }
    }
  }

  const float inv = 1.0f / l;
  const long orow = (long)(b * 2048 + q0 + wave * 16 + lq);
#pragma unroll
  for (int di = 0; di < 2; ++di) {
    u16x4 ov;
#pragma unroll
    for (int r = 0; r < 4; ++r) ov[r] = f2bf(oacc[di][r] * inv);
    *reinterpret_cast<u16x4*>(o + orow * 256 + h * 32 + di * 16 + g * 4) = ov;
  }
}

// ---------------------------------------------------------------- LayerNorm(yin_bf16 + xres_f32)
__global__ __launch_bounds__(256) void k_ln(const u16* __restrict__ yin, const float* __restrict__ xres,
                                            const float* __restrict__ gw, const float* __restrict__ bw,
                                            float* __restrict__ out) {
  const int row = blockIdx.x * 4 + (threadIdx.x >> 6);
  const int lane = threadIdx.x & 63;
  const long base = (long)row * 256 + lane * 4;
  const float4 xv = *reinterpret_cast<const float4*>(xres + base);
  const u16x4 yv = *reinterpret_cast<const u16x4*>(yin + base);
  float s0 = bf2f(yv[0]) + xv.x;
  float s1 = bf2f(yv[1]) + xv.y;
  float s2 = bf2f(yv[2]) + xv.z;
  float s3 = bf2f(yv[3]) + xv.w;
  float sum = s0 + s1 + s2 + s3;
  float sq = s0 * s0 + s1 * s1 + s2 * s2 + s3 * s3;
#pragma unroll
  for (int msk = 1; msk < 64; msk <<= 1) {
    sum += __shfl_xor(sum, msk);
    sq += __shfl_xor(sq, msk);
  }
  const float mean = sum * (1.0f / 256.0f);
  const float var = sq * (1.0f / 256.0f) - mean * mean;
  const float rstd = rsqrtf(var + 1e-5f);
  const int c = lane * 4;
  float4 ov;
  ov.x = (s0 - mean) * rstd * gw[c + 0] + bw[c + 0];
  ov.y = (s1 - mean) * rstd * gw[c + 1] + bw[c + 1];
  ov.z = (s2 - mean) * rstd * gw[c + 2] + bw[c + 2];
  ov.w = (s3 - mean) * rstd * gw[c + 3] + bw[c + 3];
  *reinterpret_cast<float4*>(out + base) = ov;
}

// ---------------------------------------------------------------- ffin = gelu_exact(gg[:, :1024]) * gg[:, 1024:]
__global__ __launch_bounds__(256) void k_gelumul(const u16* __restrict__ gg, u16* __restrict__ ffin) {
  const long i = ((long)blockIdx.x * 256 + threadIdx.x) * 8;
  const long row = i >> 10;
  const int c = (int)(i & 1023);
  const u16* p = gg + row * 2048 + c;
  const u16x8 a = *reinterpret_cast<const u16x8*>(p);
  const u16x8 b = *reinterpret_cast<const u16x8*>(p + 1024);
  u16x8 ov;
#pragma unroll
  for (int j = 0; j < 8; ++j) {
    const float xg = bf2f(a[j]);
    const float gl = 0.5f * xg * (1.0f + erff(xg * 0.70710678118654752f));
    ov[j] = f2bf(gl * bf2f(b[j]));
  }
  *reinterpret_cast<u16x8*>(ffin + i) = ov;
}

// ---------------------------------------------------------------- launch
extern "C" void kernel_launch(void* const* d_in, const int* in_sizes, int n_in,
                              void* d_out, int out_size, void* d_ws, size_t ws_size,
                              hipStream_t stream) {
  (void)in_sizes; (void)n_in; (void)out_size;
  if (ws_size < 136314880ULL) return;  // need ~136.3 MB scratch

  const float* x     = (const float*)d_in[0];
  const float* w_qkv = (const float*)d_in[1];
  const float* w_out = (const float*)d_in[2];
  const float* b_out = (const float*)d_in[3];
  const float* w1    = (const float*)d_in[4];
  const float* wv    = (const float*)d_in[5];
  const float* w2    = (const float*)d_in[6];
  const float* ln1g  = (const float*)d_in[7];
  const float* ln1b  = (const float*)d_in[8];
  const float* ln2g  = (const float*)d_in[9];
  const float* ln2b  = (const float*)d_in[10];
  float* outp = (float*)d_out;

  char* ws = (char*)d_ws;
  u16* xb    = (u16*)ws;              // 4,194,304 elems @ elt 0
  u16* wqkvb = xb + 4194304;
  u16* woutb = wqkvb + 196608;
  u16* w1b   = woutb + 65536;
  u16* wvb   = w1b + 262144;
  u16* w2b   = wvb + 262144;
  u16* qkvb  = w2b + 262144;          // elt 5,242,880 (byte 10,485,760), 12,582,912 elems
  u16* ob    = qkvb + 12582912;       // byte 35,651,584
  u16* yb    = ob + 4194304;          // byte 44,040,192
  float* x1  = (float*)(ws + 52428800);   // 16,777,216 B
  u16* gg    = (u16*)(ws + 69206016);     // 67,108,864 B
  u16* ffin  = qkvb;                  // alias (qkv+o dead by then), 33,554,432 B
  u16* ff2   = xb;                    // alias (x_bf16 dead), 8,388,608 B

  // 1. casts
  k_cast<<<5120, 256, 0, stream>>>(x, w_qkv, w_out, w1, wv, w2, xb);
  // 2. qkv = x @ w_qkv^T   [16384,768]
  k_gemm<<<dim3(128, 6), 256, 0, stream>>>(xb, wqkvb, wqkvb, 1 << 30, nullptr, qkvb, 768, 256);
  // 3. attention -> o [16384,256]
  k_attn<<<1024, 512, 0, stream>>>(qkvb, ob);
  // 4. y = o @ w_out^T + b_out
  k_gemm<<<dim3(128, 2), 256, 0, stream>>>(ob, woutb, woutb, 1 << 30, b_out, yb, 256, 256);
  // 5. x1 = LN(y + x)
  k_ln<<<4096, 256, 0, stream>>>(yb, x, ln1g, ln1b, x1);
  // 6. gg = y @ [w1; wv]^T  [16384,2048]
  k_gemm<<<dim3(128, 16), 256, 0, stream>>>(yb, w1b, wvb, 1024, nullptr, gg, 2048, 256);
  // 7. ffin = gelu(gg[:, :1024]) * gg[:, 1024:]
  k_gelumul<<<8192, 256, 0, stream>>>(gg, ffin);
  // 8. ff2 = ffin @ w2^T  [16384,256]
  k_gemm<<<dim3(128, 2), 256, 0, stream>>>(ffin, w2b, w2b, 1 << 30, nullptr, ff2, 256, 1024);
  // 9. out = LN(ff2 + x1)
  k_ln<<<4096, 256, 0, stream>>>(ff2, x1, ln2g, ln2b, outp);
}

// Round 2
// 282.409 us; speedup vs baseline: 1.2563x; 1.2563x over previous
//
#include <hip/hip_runtime.h>

typedef unsigned short u16;
typedef __bf16 bf16;
typedef __bf16 bf16x8 __attribute__((ext_vector_type(8)));
typedef float f32x4 __attribute__((ext_vector_type(4)));
typedef unsigned short u16x8 __attribute__((ext_vector_type(8)));
typedef unsigned short u16x4 __attribute__((ext_vector_type(4)));
typedef unsigned short u16x2 __attribute__((ext_vector_type(2)));

#define DEVI static __device__ __forceinline__

DEVI float bf2f(u16 h) { return __builtin_bit_cast(float, (unsigned)h << 16); }
DEVI u16 cvt_bf(float f) { return __builtin_bit_cast(u16, (bf16)f); }  // HW RTNE convert

// async global->LDS, 16B per lane; LDS dest = wave-uniform base + lane*16
DEVI void gload16(const u16* g, u16* l) {
  __builtin_amdgcn_global_load_lds(
      (const __attribute__((address_space(1))) void*)g,
      (__attribute__((address_space(3))) void*)l, 16, 0, 0);
}

// ---------------------------------------------------------------- cast fp32->bf16
__global__ __launch_bounds__(256) void k_cast(const float* __restrict__ x,
                                              const float* __restrict__ wqkv,
                                              const float* __restrict__ wout,
                                              const float* __restrict__ w1,
                                              const float* __restrict__ wv,
                                              const float* __restrict__ w2,
                                              u16* __restrict__ dst0) {
  long i = (long)blockIdx.x * 256 + threadIdx.x;
  const float* src;
  u16* dst;
  long off;
  if (i < 1048576)       { src = x;    dst = dst0;           off = i; }
  else if (i < 1097728)  { src = wqkv; dst = dst0 + 4194304; off = i - 1048576; }
  else if (i < 1114112)  { src = wout; dst = dst0 + 4390912; off = i - 1097728; }
  else if (i < 1179648)  { src = w1;   dst = dst0 + 4456448; off = i - 1114112; }
  else if (i < 1245184)  { src = wv;   dst = dst0 + 4718592; off = i - 1179648; }
  else                   { src = w2;   dst = dst0 + 4980736; off = i - 1245184; }
  float4 f = reinterpret_cast<const float4*>(src)[off];
  u16x4 o;
  o[0] = cvt_bf(f.x); o[1] = cvt_bf(f.y); o[2] = cvt_bf(f.z); o[3] = cvt_bf(f.w);
  reinterpret_cast<u16x4*>(dst)[off] = o;
}

// ---------------------------------------------------------------- GEMM: C = A * B^T (+bias)
// A [M][K] bf16, B rows = out-features (B0/B1 split at Nsplit), C [M][N] bf16.
// BMx BN tile, BK=64. global_load_lds(16B) staging into LINEAR LDS [rows][64],
// granule-XOR swizzle applied on SOURCE addr + READ addr (rule #21).
// B tile ni owns cols wc+lr*NI+ni -> lane's NI output cols contiguous -> vector stores.
template <int BM, int BN, int NI>
__global__ __launch_bounds__(256) void k_gemm(const u16* __restrict__ A, const u16* __restrict__ B0,
                                              const u16* __restrict__ B1, int Nsplit,
                                              const float* __restrict__ bias,
                                              u16* __restrict__ C, int N, int K) {
  constexpr int MI = BM / 32;
  __shared__ u16 Alds[BM * 64];
  __shared__ u16 Blds[BN * 64];
  const int m0 = blockIdx.x * BM;
  const int n0 = blockIdx.y * BN;
  const u16* Ap = A + (long)m0 * K;
  const u16* Bp = (n0 < Nsplit) ? (B0 + (long)n0 * K) : (B1 + (long)(n0 - Nsplit) * K);
  const int tid = threadIdx.x, lane = tid & 63, wave = tid >> 6;
  const int wr = (wave >> 1) * (BM / 2), wc = (wave & 1) * (BN / 2);
  const int lr = lane & 15, g = lane >> 4;
  const int sr = lane >> 3, sg = lane & 7;  // staging: 8 rows x 8 granules per call

  f32x4 acc[MI][NI] = {};
  const int nk = K >> 6;
  for (int kt = 0; kt < nk; ++kt) {
    const int kb = kt << 6;
    __syncthreads();
#pragma unroll
    for (int c = 0; c < BM / 32; ++c) {
      const int row = wave * (BM / 4) + c * 8 + sr;
      gload16(Ap + (long)row * K + kb + ((sg ^ (row & 7)) << 3),
              &Alds[(wave * (BM / 4) + c * 8) << 6]);
    }
#pragma unroll
    for (int c = 0; c < BN / 32; ++c) {
      const int row = wave * (BN / 4) + c * 8 + sr;
      gload16(Bp + (long)row * K + kb + ((sg ^ ((row / NI) & 7)) << 3),
              &Blds[(wave * (BN / 4) + c * 8) << 6]);
    }
    __syncthreads();
#pragma unroll
    for (int kk = 0; kk < 2; ++kk) {
      bf16x8 av[MI], bv[NI];
#pragma unroll
      for (int i = 0; i < MI; ++i) {
        const int ra = wr + i * 16 + lr;
        av[i] = *reinterpret_cast<const bf16x8*>(&Alds[(ra << 6) + (((kk * 4 + g) ^ (ra & 7)) << 3)]);
      }
#pragma unroll
      for (int ni = 0; ni < NI; ++ni) {
        const int rb = wc + lr * NI + ni;
        bv[ni] = *reinterpret_cast<const bf16x8*>(&Blds[(rb << 6) + (((kk * 4 + g) ^ ((rb / NI) & 7)) << 3)]);
      }
#pragma unroll
      for (int mi = 0; mi < MI; ++mi)
#pragma unroll
        for (int ni = 0; ni < NI; ++ni)
          acc[mi][ni] = __builtin_amdgcn_mfma_f32_16x16x32_bf16(av[mi], bv[ni], acc[mi][ni], 0, 0, 0);
    }
  }
  const int colb = n0 + wc + lr * NI;
  float bvv[NI];
#pragma unroll
  for (int ni = 0; ni < NI; ++ni) bvv[ni] = bias ? bias[colb + ni] : 0.0f;
#pragma unroll
  for (int mi = 0; mi < MI; ++mi) {
#pragma unroll
    for (int r = 0; r < 4; ++r) {
      const long row = m0 + wr + mi * 16 + g * 4 + r;
      if constexpr (NI == 4) {
        u16x4 v;
#pragma unroll
        for (int ni = 0; ni < 4; ++ni) v[ni] = cvt_bf(acc[mi][ni][r] + bvv[ni]);
        *reinterpret_cast<u16x4*>(C + row * N + colb) = v;
      } else {
        u16x2 v;
#pragma unroll
        for (int ni = 0; ni < 2; ++ni) v[ni] = cvt_bf(acc[mi][ni][r] + bvv[ni]);
        *reinterpret_cast<u16x2*>(C + row * N + colb) = v;
      }
    }
  }
}

// ---------------------------------------------------------------- flash attention
// qkv [16384][768] bf16 (Q 0..255, K 256..511, V 512..767; head h at h*32).
// Grid 1024: id%64 = bh, id/64 = 128-row q-tile. 8 waves x 16 q-rows.
// Swapped QK^T (mfma(K,Q)): lane owns q=lane&15; softmax in exp2 domain
// (Q pre-scaled by hd^-0.5 * log2e). P stored row-major per-wave [16][72]:
// b64 writes, b128 B-fragment reads. K staged via global_load_lds.
__global__ __launch_bounds__(512) void k_attn(const u16* __restrict__ qkv, u16* __restrict__ o) {
  __shared__ u16 Klds[64 * 32];
  __shared__ u16 Vtlds[32 * 72];
  __shared__ u16 Plds[8 * 16 * 72];
  const int id = blockIdx.x;
  const int qt = id >> 6;
  const int bh = id & 63;
  const int b = bh >> 3, h = bh & 7;
  const int tid = threadIdx.x;
  const int wave = tid >> 6, lane = tid & 63;
  const int lq = lane & 15, g = lane >> 4;
  const int q0 = qt * 128;
  const long qrow = (long)(b * 2048 + q0 + wave * 16 + lq);
  u16x8 qraw = *reinterpret_cast<const u16x8*>(qkv + qrow * 768 + h * 32 + g * 8);
  bf16x8 qf;
#pragma unroll
  for (int j = 0; j < 8; ++j) qf[j] = (bf16)(bf2f(qraw[j]) * 0.25503486f);  // hd^-.5 * log2e

  float m = -1e30f, l = 0.0f;
  f32x4 oacc[2] = {};
  const f32x4 zero = {0.0f, 0.0f, 0.0f, 0.0f};
  u16* Pw = &Plds[wave * 16 * 72];

  for (int kt = 0; kt < 32; ++kt) {
    __syncthreads();
    const long kbase = (long)(b * 2048 + kt * 64);
    if (wave < 4) {  // stage K [64][32] linear via global_load_lds (16 rows per wave)
      gload16(qkv + (kbase + wave * 16 + (lane >> 2)) * 768 + 256 + h * 32 + (lane & 3) * 8,
              &Klds[wave * 16 * 32]);
    } else {         // stage V transposed -> Vtlds [32 d][64 k] stride 72
      const int st = tid - 256;
      const int k = st >> 2, dc = (st & 3) * 8;
      u16x8 vv = *reinterpret_cast<const u16x8*>(qkv + (kbase + k) * 768 + 512 + h * 32 + dc);
#pragma unroll
      for (int j = 0; j < 8; ++j) Vtlds[(dc + j) * 72 + k] = vv[j];
    }
    __syncthreads();

    f32x4 s[4];
#pragma unroll
    for (int f = 0; f < 4; ++f) {
      bf16x8 kf = *reinterpret_cast<const bf16x8*>(&Klds[(f * 16 + lq) * 32 + g * 8]);
      s[f] = __builtin_amdgcn_mfma_f32_16x16x32_bf16(kf, qf, zero, 0, 0, 0);
    }

    float tmax = -1e30f;
#pragma unroll
    for (int f = 0; f < 4; ++f)
#pragma unroll
      for (int r = 0; r < 4; ++r) tmax = fmaxf(tmax, s[f][r]);
    tmax = fmaxf(tmax, __shfl_xor(tmax, 16));
    tmax = fmaxf(tmax, __shfl_xor(tmax, 32));
    const float mnew = fmaxf(m, tmax);
    const float alpha = exp2f(m - mnew);
    float rsum = 0.0f;
#pragma unroll
    for (int f = 0; f < 4; ++f) {
      u16x4 pk;
#pragma unroll
      for (int r = 0; r < 4; ++r) {
        const float p = exp2f(s[f][r] - mnew);
        rsum += p;
        pk[r] = cvt_bf(p);
      }
      *reinterpret_cast<u16x4*>(Pw + lq * 72 + f * 16 + g * 4) = pk;  // b64, wave-private
    }
    rsum += __shfl_xor(rsum, 16);
    rsum += __shfl_xor(rsum, 32);
    l = l * alpha + rsum;
    m = mnew;
#pragma unroll
    for (int di = 0; di < 2; ++di)
#pragma unroll
      for (int r = 0; r < 4; ++r) oacc[di][r] *= alpha;

#pragma unroll
    for (int ks = 0; ks < 2; ++ks) {
      const bf16x8 pf = *reinterpret_cast<const bf16x8*>(Pw + lq * 72 + ks * 32 + g * 8);
#pragma unroll
      for (int di = 0; di < 2; ++di) {
        bf16x8 vf = *reinterpret_cast<const bf16x8*>(&Vtlds[(di * 16 + lq) * 72 + ks * 32 + g * 8]);
        oacc[di] = __builtin_amdgcn_mfma_f32_16x16x32_bf16(vf, pf, oacc[di], 0, 0, 0);
      }
    }
  }

  const float inv = 1.0f / l;
  const long orow = (long)(b * 2048 + q0 + wave * 16 + lq);
#pragma unroll
  for (int di = 0; di < 2; ++di) {
    u16x4 ov;
#pragma unroll
    for (int r = 0; r < 4; ++r) ov[r] = cvt_bf(oacc[di][r] * inv);
    *reinterpret_cast<u16x4*>(o + orow * 256 + h * 32 + di * 16 + g * 4) = ov;
  }
}

// ---------------------------------------------------------------- LayerNorm(yin_bf16 + xres_f32)
__global__ __launch_bounds__(256) void k_ln(const u16* __restrict__ yin, const float* __restrict__ xres,
                                            const float* __restrict__ gw, const float* __restrict__ bw,
                                            float* __restrict__ out) {
  const int row = blockIdx.x * 4 + (threadIdx.x >> 6);
  const int lane = threadIdx.x & 63;
  const long base = (long)row * 256 + lane * 4;
  const float4 xv = *reinterpret_cast<const float4*>(xres + base);
  const u16x4 yv = *reinterpret_cast<const u16x4*>(yin + base);
  float s0 = bf2f(yv[0]) + xv.x;
  float s1 = bf2f(yv[1]) + xv.y;
  float s2 = bf2f(yv[2]) + xv.z;
  float s3 = bf2f(yv[3]) + xv.w;
  float sum = s0 + s1 + s2 + s3;
  float sq = s0 * s0 + s1 * s1 + s2 * s2 + s3 * s3;
#pragma unroll
  for (int msk = 1; msk < 64; msk <<= 1) {
    sum += __shfl_xor(sum, msk);
    sq += __shfl_xor(sq, msk);
  }
  const float mean = sum * (1.0f / 256.0f);
  const float var = sq * (1.0f / 256.0f) - mean * mean;
  const float rstd = rsqrtf(var + 1e-5f);
  const int c = lane * 4;
  float4 ov;
  ov.x = (s0 - mean) * rstd * gw[c + 0] + bw[c + 0];
  ov.y = (s1 - mean) * rstd * gw[c + 1] + bw[c + 1];
  ov.z = (s2 - mean) * rstd * gw[c + 2] + bw[c + 2];
  ov.w = (s3 - mean) * rstd * gw[c + 3] + bw[c + 3];
  *reinterpret_cast<float4*>(out + base) = ov;
}

// ---------------------------------------------------------------- ffin = gelu_exact(gg[:, :1024]) * gg[:, 1024:]
__global__ __launch_bounds__(256) void k_gelumul(const u16* __restrict__ gg, u16* __restrict__ ffin) {
  const long i = ((long)blockIdx.x * 256 + threadIdx.x) * 8;
  const long row = i >> 10;
  const int c = (int)(i & 1023);
  const u16* p = gg + row * 2048 + c;
  const u16x8 a = *reinterpret_cast<const u16x8*>(p);
  const u16x8 b = *reinterpret_cast<const u16x8*>(p + 1024);
  u16x8 ov;
#pragma unroll
  for (int j = 0; j < 8; ++j) {
    const float xg = bf2f(a[j]);
    const float gl = 0.5f * xg * (1.0f + erff(xg * 0.70710678118654752f));
    ov[j] = cvt_bf(gl * bf2f(b[j]));
  }
  *reinterpret_cast<u16x8*>(ffin + i) = ov;
}

// ---------------------------------------------------------------- launch
extern "C" void kernel_launch(void* const* d_in, const int* in_sizes, int n_in,
                              void* d_out, int out_size, void* d_ws, size_t ws_size,
                              hipStream_t stream) {
  (void)in_sizes; (void)n_in; (void)out_size;
  if (ws_size < 136314880ULL) return;  // need ~136.3 MB scratch

  const float* x     = (const float*)d_in[0];
  const float* w_qkv = (const float*)d_in[1];
  const float* w_out = (const float*)d_in[2];
  const float* b_out = (const float*)d_in[3];
  const float* w1    = (const float*)d_in[4];
  const float* wv    = (const float*)d_in[5];
  const float* w2    = (const float*)d_in[6];
  const float* ln1g  = (const float*)d_in[7];
  const float* ln1b  = (const float*)d_in[8];
  const float* ln2g  = (const float*)d_in[9];
  const float* ln2b  = (const float*)d_in[10];
  float* outp = (float*)d_out;

  char* ws = (char*)d_ws;
  u16* xb    = (u16*)ws;              // 4,194,304 elems
  u16* wqkvb = xb + 4194304;
  u16* woutb = wqkvb + 196608;
  u16* w1b   = woutb + 65536;
  u16* wvb   = w1b + 262144;
  u16* w2b   = wvb + 262144;
  u16* qkvb  = w2b + 262144;          // 12,582,912 elems
  u16* ob    = qkvb + 12582912;
  u16* yb    = ob + 4194304;
  float* x1  = (float*)(ws + 52428800);
  u16* gg    = (u16*)(ws + 69206016);
  u16* ffin  = qkvb;                  // alias (qkv+o dead by then)
  u16* ff2   = xb;                    // alias (x_bf16 dead)

  // 1. casts
  k_cast<<<5120, 256, 0, stream>>>(x, w_qkv, w_out, w1, wv, w2, xb);
  // 2. qkv = x @ w_qkv^T   [16384,768]
  k_gemm<128, 128, 4><<<dim3(128, 6), 256, 0, stream>>>(xb, wqkvb, wqkvb, 1 << 30, nullptr, qkvb, 768, 256);
  // 3. attention -> o [16384,256]
  k_attn<<<1024, 512, 0, stream>>>(qkvb, ob);
  // 4. y = o @ w_out^T + b_out
  k_gemm<128, 64, 2><<<dim3(128, 4), 256, 0, stream>>>(ob, woutb, woutb, 1 << 30, b_out, yb, 256, 256);
  // 5. x1 = LN(y + x)
  k_ln<<<4096, 256, 0, stream>>>(yb, x, ln1g, ln1b, x1);
  // 6. gg = y @ [w1; wv]^T  [16384,2048]
  k_gemm<128, 128, 4><<<dim3(128, 16), 256, 0, stream>>>(yb, w1b, wvb, 1024, nullptr, gg, 2048, 256);
  // 7. ffin = gelu(gg[:, :1024]) * gg[:, 1024:]
  k_gelumul<<<8192, 256, 0, stream>>>(gg, ffin);
  // 8. ff2 = ffin @ w2^T  [16384,256]
  k_gemm<128, 64, 2><<<dim3(128, 4), 256, 0, stream>>>(ffin, w2b, w2b, 1 << 30, nullptr, ff2, 256, 1024);
  // 9. out = LN(ff2 + x1)
  k_ln<<<4096, 256, 0, stream>>>(ff2, x1, ln2g, ln2b, outp);
}

// Round 3
// 269.728 us; speedup vs baseline: 1.3153x; 1.0470x over previous
//
#include <hip/hip_runtime.h>

typedef unsigned short u16;
typedef __bf16 bf16;
typedef __bf16 bf16x8 __attribute__((ext_vector_type(8)));
typedef float f32x4 __attribute__((ext_vector_type(4)));
typedef unsigned short u16x8 __attribute__((ext_vector_type(8)));
typedef unsigned short u16x4 __attribute__((ext_vector_type(4)));
typedef unsigned short u16x2 __attribute__((ext_vector_type(2)));

#define DEVI static __device__ __forceinline__

DEVI float bf2f(u16 h) { return __builtin_bit_cast(float, (unsigned)h << 16); }
DEVI u16 cvt_bf(float f) { return __builtin_bit_cast(u16, (bf16)f); }  // HW RTNE convert

// async global->LDS, 16B/lane; LDS dest = wave-uniform base, HW adds lane*16
DEVI void gload16(const u16* g, u16* l) {
  __builtin_amdgcn_global_load_lds(
      (const __attribute__((address_space(1))) void*)g,
      (__attribute__((address_space(3))) void*)l, 16, 0, 0);
}

DEVI float gelu_exact(float x) {
  return 0.5f * x * (1.0f + erff(x * 0.70710678118654752f));
}

// ---------------------------------------------------------------- cast fp32->bf16
__global__ __launch_bounds__(256) void k_cast(const float* __restrict__ x,
                                              const float* __restrict__ wqkv,
                                              const float* __restrict__ wout,
                                              const float* __restrict__ w1,
                                              const float* __restrict__ wv,
                                              const float* __restrict__ w2,
                                              u16* __restrict__ dst0) {
  long i = (long)blockIdx.x * 256 + threadIdx.x;
  const float* src;
  u16* dst;
  long off;
  if (i < 1048576)       { src = x;    dst = dst0;           off = i; }
  else if (i < 1097728)  { src = wqkv; dst = dst0 + 4194304; off = i - 1048576; }
  else if (i < 1114112)  { src = wout; dst = dst0 + 4390912; off = i - 1097728; }
  else if (i < 1179648)  { src = w1;   dst = dst0 + 4456448; off = i - 1114112; }
  else if (i < 1245184)  { src = wv;   dst = dst0 + 4718592; off = i - 1179648; }
  else                   { src = w2;   dst = dst0 + 4980736; off = i - 1245184; }
  float4 f = reinterpret_cast<const float4*>(src)[off];
  u16x4 o;
  o[0] = cvt_bf(f.x); o[1] = cvt_bf(f.y); o[2] = cvt_bf(f.z); o[3] = cvt_bf(f.w);
  reinterpret_cast<u16x4*>(dst)[off] = o;
}

// ---------------------------------------------------------------- GEMM: C = A * B^T (+bias)
template <int BM, int BN, int NI>
__global__ __launch_bounds__(256) void k_gemm(const u16* __restrict__ A, const u16* __restrict__ B0,
                                              const u16* __restrict__ B1, int Nsplit,
                                              const float* __restrict__ bias,
                                              u16* __restrict__ C, int N, int K) {
  constexpr int MI = BM / 32;
  __shared__ u16 Alds[BM * 64];
  __shared__ u16 Blds[BN * 64];
  const int m0 = blockIdx.x * BM;
  const int n0 = blockIdx.y * BN;
  const u16* Ap = A + (long)m0 * K;
  const u16* Bp = (n0 < Nsplit) ? (B0 + (long)n0 * K) : (B1 + (long)(n0 - Nsplit) * K);
  const int tid = threadIdx.x, lane = tid & 63, wave = tid >> 6;
  const int wr = (wave >> 1) * (BM / 2), wc = (wave & 1) * (BN / 2);
  const int lr = lane & 15, g = lane >> 4;
  const int sr = lane >> 3, sg = lane & 7;

  f32x4 acc[MI][NI] = {};
  const int nk = K >> 6;
  for (int kt = 0; kt < nk; ++kt) {
    const int kb = kt << 6;
    __syncthreads();
#pragma unroll
    for (int c = 0; c < BM / 32; ++c) {
      const int row = wave * (BM / 4) + c * 8 + sr;
      gload16(Ap + (long)row * K + kb + ((sg ^ (row & 7)) << 3),
              &Alds[(wave * (BM / 4) + c * 8) << 6]);
    }
#pragma unroll
    for (int c = 0; c < BN / 32; ++c) {
      const int row = wave * (BN / 4) + c * 8 + sr;
      gload16(Bp + (long)row * K + kb + ((sg ^ ((row / NI) & 7)) << 3),
              &Blds[(wave * (BN / 4) + c * 8) << 6]);
    }
    __syncthreads();
#pragma unroll
    for (int kk = 0; kk < 2; ++kk) {
      bf16x8 av[MI], bv[NI];
#pragma unroll
      for (int i = 0; i < MI; ++i) {
        const int ra = wr + i * 16 + lr;
        av[i] = *reinterpret_cast<const bf16x8*>(&Alds[(ra << 6) + (((kk * 4 + g) ^ (ra & 7)) << 3)]);
      }
#pragma unroll
      for (int ni = 0; ni < NI; ++ni) {
        const int rb = wc + lr * NI + ni;
        bv[ni] = *reinterpret_cast<const bf16x8*>(&Blds[(rb << 6) + (((kk * 4 + g) ^ ((rb / NI) & 7)) << 3)]);
      }
#pragma unroll
      for (int mi = 0; mi < MI; ++mi)
#pragma unroll
        for (int ni = 0; ni < NI; ++ni)
          acc[mi][ni] = __builtin_amdgcn_mfma_f32_16x16x32_bf16(av[mi], bv[ni], acc[mi][ni], 0, 0, 0);
    }
  }
  const int colb = n0 + wc + lr * NI;
  float bvv[NI];
#pragma unroll
  for (int ni = 0; ni < NI; ++ni) bvv[ni] = bias ? bias[colb + ni] : 0.0f;
#pragma unroll
  for (int mi = 0; mi < MI; ++mi) {
#pragma unroll
    for (int r = 0; r < 4; ++r) {
      const long row = m0 + wr + mi * 16 + g * 4 + r;
      if constexpr (NI == 4) {
        u16x4 v;
#pragma unroll
        for (int ni = 0; ni < 4; ++ni) v[ni] = cvt_bf(acc[mi][ni][r] + bvv[ni]);
        *reinterpret_cast<u16x4*>(C + row * N + colb) = v;
      } else {
        u16x2 v;
#pragma unroll
        for (int ni = 0; ni < 2; ++ni) v[ni] = cvt_bf(acc[mi][ni][r] + bvv[ni]);
        *reinterpret_cast<u16x2*>(C + row * N + colb) = v;
      }
    }
  }
}

// ---------------------------------------------------------------- GEGLU-fused FFN-up
// ffin[:, j] = gelu(A@w1^T)[:, j] * (A@wv^T)[:, j]. B rows interleaved: rb even->w1, odd->wv.
// BM=128, BN=64 (=32 out cols), 4 waves by rows (wr=wave*32), NI=4 -> lane owns 2 (w1,wv) pairs.
__global__ __launch_bounds__(256) void k_glu(const u16* __restrict__ A, const u16* __restrict__ W1,
                                             const u16* __restrict__ Wv, u16* __restrict__ C) {
  constexpr int K = 256, N = 1024;
  __shared__ u16 Alds[128 * 64];
  __shared__ u16 Blds[64 * 64];
  const int m0 = blockIdx.x * 128;
  const int n0h = blockIdx.y * 32;
  const u16* Ap = A + (long)m0 * K;
  const int tid = threadIdx.x, lane = tid & 63, wave = tid >> 6;
  const int lr = lane & 15, g = lane >> 4;
  const int sr = lane >> 3, sg = lane & 7;

  f32x4 acc[2][4] = {};
  for (int kt = 0; kt < 4; ++kt) {
    const int kb = kt << 6;
    __syncthreads();
#pragma unroll
    for (int c = 0; c < 4; ++c) {
      const int row = wave * 32 + c * 8 + sr;
      gload16(Ap + (long)row * K + kb + ((sg ^ (row & 7)) << 3), &Alds[(wave * 32 + c * 8) << 6]);
    }
#pragma unroll
    for (int c = 0; c < 2; ++c) {
      const int row = wave * 16 + c * 8 + sr;
      const u16* bp = (row & 1) ? Wv : W1;
      gload16(bp + (long)(n0h + (row >> 1)) * K + kb + ((sg ^ ((row >> 2) & 7)) << 3),
              &Blds[(wave * 16 + c * 8) << 6]);
    }
    __syncthreads();
#pragma unroll
    for (int kk = 0; kk < 2; ++kk) {
      bf16x8 av[2], bv[4];
#pragma unroll
      for (int i = 0; i < 2; ++i) {
        const int ra = wave * 32 + i * 16 + lr;
        av[i] = *reinterpret_cast<const bf16x8*>(&Alds[(ra << 6) + (((kk * 4 + g) ^ (ra & 7)) << 3)]);
      }
#pragma unroll
      for (int ni = 0; ni < 4; ++ni) {
        const int rb = lr * 4 + ni;
        bv[ni] = *reinterpret_cast<const bf16x8*>(&Blds[(rb << 6) + (((kk * 4 + g) ^ ((rb >> 2) & 7)) << 3)]);
      }
#pragma unroll
      for (int mi = 0; mi < 2; ++mi)
#pragma unroll
        for (int ni = 0; ni < 4; ++ni)
          acc[mi][ni] = __builtin_amdgcn_mfma_f32_16x16x32_bf16(av[mi], bv[ni], acc[mi][ni], 0, 0, 0);
    }
  }
  const int j0 = n0h + lr * 2;
#pragma unroll
  for (int mi = 0; mi < 2; ++mi) {
#pragma unroll
    for (int r = 0; r < 4; ++r) {
      const long row = m0 + wave * 32 + mi * 16 + g * 4 + r;
      u16x2 v;
      v[0] = cvt_bf(gelu_exact(acc[mi][0][r]) * acc[mi][1][r]);
      v[1] = cvt_bf(gelu_exact(acc[mi][2][r]) * acc[mi][3][r]);
      *reinterpret_cast<u16x2*>(C + row * N + j0) = v;
    }
  }
}

// ---------------------------------------------------------------- V transpose: vt[(bh*32+d)*2048+n]
__global__ __launch_bounds__(256) void k_vt(const u16* __restrict__ qkv, u16* __restrict__ vt) {
  const int bh = blockIdx.x & 63, nt = blockIdx.x >> 6;
  const int b = bh >> 3, h = bh & 7;
  const int wave = threadIdx.x >> 6, lane = threadIdx.x & 63;
  const int dcol = wave * 8;
#pragma unroll
  for (int i = 0; i < 4; ++i) {
    const int nn = nt * 256 + i * 64 + lane;
    u16x8 v = *reinterpret_cast<const u16x8*>(qkv + (long)(b * 2048 + nn) * 768 + 512 + h * 32 + dcol);
#pragma unroll
    for (int j = 0; j < 8; ++j)
      vt[(long)(bh * 32 + dcol + j) * 2048 + nn] = v[j];  // lanes -> 128B contiguous
  }
}

// ---------------------------------------------------------------- flash attention
// KVBLK=128. Klds [64 r][8 gran] packs k-tiles {r, 64+r}; Vlds [32 d][16 gran];
// 16B-granule XOR swizzle (phys = logical ^ (row&7)) pre-applied on global src (rule #21).
// Single-barrier double-buffered staging (m97 pattern). P strip per-wave [16][64] swizzled.
__global__ __launch_bounds__(512) void k_attn(const u16* __restrict__ qkv, const u16* __restrict__ vt,
                                              u16* __restrict__ o) {
  __shared__ u16 Klds[2 * 4096];
  __shared__ u16 Vlds[2 * 4096];
  __shared__ u16 Plds[8 * 1024];
  const int id = blockIdx.x;
  const int qt = id >> 6, bh = id & 63;
  const int b = bh >> 3, h = bh & 7;
  const int tid = threadIdx.x, wave = tid >> 6, lane = tid & 63;
  const int lq = lane & 15, g = lane >> 4, lqh = lq & 7;

  const long qrow = (long)(b * 2048 + qt * 128 + wave * 16 + lq);
  u16x8 qraw = *reinterpret_cast<const u16x8*>(qkv + qrow * 768 + h * 32 + g * 8);
  bf16x8 qf;
#pragma unroll
  for (int j = 0; j < 8; ++j) qf[j] = (bf16)(bf2f(qraw[j]) * 0.25503486f);  // hd^-.5 * log2e

  // staging sources (pre-swizzled): K thread covers (r=tid>>3, gp=tid&7)
  const int rK = tid >> 3, gpK = tid & 7, lK = gpK ^ (rK & 7);
  const u16* ksrc = qkv + (long)(b * 2048 + (lK >> 2) * 64 + rK) * 768 + 256 + h * 32 + (lK & 3) * 8;
  // Vt thread covers (d=tid>>4, gp=tid&15)
  const int dV = tid >> 4, gpV = tid & 15, lV = (gpV & 8) | ((gpV & 7) ^ (dV & 7));
  const u16* vsrc = vt + (long)(bh * 32 + dV) * 2048 + lV * 8;
  u16* kdst = Klds + wave * 512;  // HW appends lane*16B
  u16* vdst = Vlds + wave * 512;

  gload16(ksrc, kdst);
  gload16(vsrc, vdst);

  float m = -1e30f, l = 0.0f;
  f32x4 oacc[2] = {};
  const f32x4 zero = {0.0f, 0.0f, 0.0f, 0.0f};
  u16* Pw = Plds + wave * 1024;

  for (int kt = 0; kt < 16; ++kt) {
    const int bo = (kt & 1) * 4096;
    __syncthreads();  // drains vmcnt -> buf(kt) ready; prev iter's reads done
    if (kt + 1 < 16) {
      const int nbo = ((kt + 1) & 1) * 4096;
      gload16(ksrc + (long)(kt + 1) * 98304, kdst + nbo);
      gload16(vsrc + (kt + 1) * 128, vdst + nbo);
    }
    // QK^T: s[f][r] = S[k=f*16+g*4+r][q=lq]
    f32x4 s[8];
#pragma unroll
    for (int f = 0; f < 8; ++f) {
      const bf16x8 kf = *reinterpret_cast<const bf16x8*>(
          &Klds[bo + (((f & 3) * 16 + lq) << 6) + ((((f >> 2) * 4 + g) ^ lqh) << 3)]);
      s[f] = __builtin_amdgcn_mfma_f32_16x16x32_bf16(kf, qf, zero, 0, 0, 0);
    }
    // online softmax (exp2 domain)
    float tmax = -1e30f;
#pragma unroll
    for (int f = 0; f < 8; ++f)
#pragma unroll
      for (int r = 0; r < 4; ++r) tmax = fmaxf(tmax, s[f][r]);
    tmax = fmaxf(tmax, __shfl_xor(tmax, 16));
    tmax = fmaxf(tmax, __shfl_xor(tmax, 32));
    const float mnew = fmaxf(m, tmax);
    const float alpha = exp2f(m - mnew);
    float rsum = 0.0f;
#pragma unroll
    for (int f = 0; f < 8; ++f)
#pragma unroll
      for (int r = 0; r < 4; ++r) {
        const float p = exp2f(s[f][r] - mnew);
        s[f][r] = p;
        rsum += p;
      }
    rsum += __shfl_xor(rsum, 16);
    rsum += __shfl_xor(rsum, 32);
    l = l * alpha + rsum;
    m = mnew;
#pragma unroll
    for (int di = 0; di < 2; ++di)
#pragma unroll
      for (int r = 0; r < 4; ++r) oacc[di][r] *= alpha;

    // PV in two passes over the 64-wide P strip
#pragma unroll
    for (int pass = 0; pass < 2; ++pass) {
#pragma unroll
      for (int fi = 0; fi < 4; ++fi) {
        const int f = pass * 4 + fi;
        u16x4 pk;
#pragma unroll
        for (int r = 0; r < 4; ++r) pk[r] = cvt_bf(s[f][r]);
        *reinterpret_cast<u16x4*>(
            &Pw[(lq << 6) + (((fi * 2 + (g >> 1)) ^ lqh) << 3) + ((g & 1) << 2)]) = pk;
      }
#pragma unroll
      for (int ks2 = 0; ks2 < 2; ++ks2) {
        const bf16x8 pf = *reinterpret_cast<const bf16x8*>(
            &Pw[(lq << 6) + (((ks2 * 4 + g) ^ lqh) << 3)]);
        const int gl = (pass * 2 + ks2) * 4 + g;
        const int gp = (gl & 8) | ((gl & 7) ^ lqh);
#pragma unroll
        for (int di = 0; di < 2; ++di) {
          const bf16x8 vf = *reinterpret_cast<const bf16x8*>(
              &Vlds[bo + (((di * 16 + lq)) << 7) + (gp << 3)]);
          oacc[di] = __builtin_amdgcn_mfma_f32_16x16x32_bf16(vf, pf, oacc[di], 0, 0, 0);
        }
      }
    }
  }

  const float inv = 1.0f / l;
  const long orow = (long)(b * 2048 + qt * 128 + wave * 16 + lq);
#pragma unroll
  for (int di = 0; di < 2; ++di) {
    u16x4 ov;
#pragma unroll
    for (int r = 0; r < 4; ++r) ov[r] = cvt_bf(oacc[di][r] * inv);
    *reinterpret_cast<u16x4*>(o + orow * 256 + h * 32 + di * 16 + g * 4) = ov;
  }
}

// ---------------------------------------------------------------- LayerNorm(yin_bf16 + xres_f32)
__global__ __launch_bounds__(256) void k_ln(const u16* __restrict__ yin, const float* __restrict__ xres,
                                            const float* __restrict__ gw, const float* __restrict__ bw,
                                            float* __restrict__ out) {
  const int row = blockIdx.x * 4 + (threadIdx.x >> 6);
  const int lane = threadIdx.x & 63;
  const long base = (long)row * 256 + lane * 4;
  const float4 xv = *reinterpret_cast<const float4*>(xres + base);
  const u16x4 yv = *reinterpret_cast<const u16x4*>(yin + base);
  float s0 = bf2f(yv[0]) + xv.x;
  float s1 = bf2f(yv[1]) + xv.y;
  float s2 = bf2f(yv[2]) + xv.z;
  float s3 = bf2f(yv[3]) + xv.w;
  float sum = s0 + s1 + s2 + s3;
  float sq = s0 * s0 + s1 * s1 + s2 * s2 + s3 * s3;
#pragma unroll
  for (int msk = 1; msk < 64; msk <<= 1) {
    sum += __shfl_xor(sum, msk);
    sq += __shfl_xor(sq, msk);
  }
  const float mean = sum * (1.0f / 256.0f);
  const float var = sq * (1.0f / 256.0f) - mean * mean;
  const float rstd = rsqrtf(var + 1e-5f);
  const int c = lane * 4;
  float4 ov;
  ov.x = (s0 - mean) * rstd * gw[c + 0] + bw[c + 0];
  ov.y = (s1 - mean) * rstd * gw[c + 1] + bw[c + 1];
  ov.z = (s2 - mean) * rstd * gw[c + 2] + bw[c + 2];
  ov.w = (s3 - mean) * rstd * gw[c + 3] + bw[c + 3];
  *reinterpret_cast<float4*>(out + base) = ov;
}

// ---------------------------------------------------------------- launch
extern "C" void kernel_launch(void* const* d_in, const int* in_sizes, int n_in,
                              void* d_out, int out_size, void* d_ws, size_t ws_size,
                              hipStream_t stream) {
  (void)in_sizes; (void)n_in; (void)out_size;
  if (ws_size < 136314880ULL) return;

  const float* x     = (const float*)d_in[0];
  const float* w_qkv = (const float*)d_in[1];
  const float* w_out = (const float*)d_in[2];
  const float* b_out = (const float*)d_in[3];
  const float* w1    = (const float*)d_in[4];
  const float* wv    = (const float*)d_in[5];
  const float* w2    = (const float*)d_in[6];
  const float* ln1g  = (const float*)d_in[7];
  const float* ln1b  = (const float*)d_in[8];
  const float* ln2g  = (const float*)d_in[9];
  const float* ln2b  = (const float*)d_in[10];
  float* outp = (float*)d_out;

  char* ws = (char*)d_ws;
  u16* xb    = (u16*)ws;               // 8,388,608 B
  u16* wqkvb = xb + 4194304;
  u16* woutb = wqkvb + 196608;
  u16* w1b   = woutb + 65536;
  u16* wvb   = w1b + 262144;
  u16* w2b   = wvb + 262144;
  u16* qkvb  = w2b + 262144;           // @10,485,760 (25.2 MB)
  u16* ob    = qkvb + 12582912;        // @35,651,584 (8.4 MB)
  u16* yb    = ob + 4194304;           // @44,040,192 (8.4 MB)
  float* x1  = (float*)(ws + 52428800);  // 16.8 MB
  u16* vtb   = (u16*)(ws + 69206016);    // 8.4 MB (old gg region)
  u16* ffin  = qkvb;                   // alias qkvb+ob (dead after attn/wout)
  u16* ff2   = xb;                     // alias xb

  k_cast<<<5120, 256, 0, stream>>>(x, w_qkv, w_out, w1, wv, w2, xb);
  k_gemm<128, 128, 4><<<dim3(128, 6), 256, 0, stream>>>(xb, wqkvb, wqkvb, 1 << 30, nullptr, qkvb, 768, 256);
  k_vt<<<512, 256, 0, stream>>>(qkvb, vtb);
  k_attn<<<1024, 512, 0, stream>>>(qkvb, vtb, ob);
  k_gemm<128, 64, 2><<<dim3(128, 4), 256, 0, stream>>>(ob, woutb, woutb, 1 << 30, b_out, yb, 256, 256);
  k_ln<<<4096, 256, 0, stream>>>(yb, x, ln1g, ln1b, x1);
  k_glu<<<dim3(128, 32), 256, 0, stream>>>(yb, w1b, wvb, ffin);
  k_gemm<128, 64, 2><<<dim3(128, 4), 256, 0, stream>>>(ffin, w2b, w2b, 1 << 30, nullptr, ff2, 256, 1024);
  k_ln<<<4096, 256, 0, stream>>>(ff2, x1, ln2g, ln2b, outp);
}